// Round 1
// baseline (1855.173 us; speedup 1.0000x reference)
//
#include <hip/hip_runtime.h>
#include <hip/hip_bf16.h>
#include <math.h>

#define N_LAYERS 3
#define ENT 64
#define NODE_DIM 128

__device__ __forceinline__ float wave_sum(float v) {
#pragma unroll
    for (int off = 32; off >= 1; off >>= 1) v += __shfl_xor(v, off, 64);
    return v;
}

// Kernel 1: P[n][l][s][j] = sum_k nf[n][k] * W1[l][s*128+k][j]
// P layout: [nNodes][384] where 384 = l*128 + s*64 + j
__global__ __launch_bounds__(384) void proj_kernel(
    const float* __restrict__ nf, const float* __restrict__ W1,
    float* __restrict__ P, int nNodes)
{
    __shared__ float nfs[16 * NODE_DIM];
    const int tid = threadIdx.x;
    const int n0 = blockIdx.x * 16;

    // stage 16 nodes' features (coalesced)
    for (int i = tid; i < 16 * NODE_DIM; i += 384) {
        int g = n0 * NODE_DIM + i;
        nfs[i] = (g < nNodes * NODE_DIM) ? nf[g] : 0.f;
    }
    __syncthreads();

    const int l = tid >> 7;
    const int rem = tid & 127;
    const int s = rem >> 6;
    const int j = rem & 63;
    const float* wp = W1 + (l * 256 + s * 128) * 64 + j;

    float acc[16];
#pragma unroll
    for (int i = 0; i < 16; ++i) acc[i] = 0.f;

    for (int k = 0; k < NODE_DIM; k += 4) {
        const float w0 = wp[(k + 0) * 64];
        const float w1 = wp[(k + 1) * 64];
        const float w2 = wp[(k + 2) * 64];
        const float w3 = wp[(k + 3) * 64];
#pragma unroll
        for (int i = 0; i < 16; ++i) {
            const float4 v = *(const float4*)&nfs[i * NODE_DIM + k];
            acc[i] += v.x * w0 + v.y * w1 + v.z * w2 + v.w * w3;
        }
    }
#pragma unroll
    for (int i = 0; i < 16; ++i) {
        int n = n0 + i;
        if (n < nNodes) P[n * 384 + tid] = acc[i];
    }
}

// Kernel 2: fused per-edge pipeline. One wave per edge; lane = channel.
#define WSTRIDE 68  // 68 floats = 272B = 17*16B: float4-aligned, bank-spread
__global__ __launch_bounds__(1024, 1) void edge_kernel(
    const float* __restrict__ P, const int* __restrict__ ei,
    const float* __restrict__ b1, const float* __restrict__ W2,
    const float* __restrict__ b2, const float* __restrict__ gamma,
    const float* __restrict__ beta, const float* __restrict__ Mw,
    const float* __restrict__ bell, float* __restrict__ out, int E)
{
    __shared__ float W2t[N_LAYERS][ENT * WSTRIDE];
    __shared__ float Mt[N_LAYERS][ENT * WSTRIDE];
    __shared__ float b1s[N_LAYERS][ENT], b2s[N_LAYERS][ENT];
    __shared__ float gs[N_LAYERS][ENT], bs[N_LAYERS][ENT];
    __shared__ float hbuf[16][ENT];

    const int tid = threadIdx.x;

    // stage transposed weights: W2t[l][j*WSTRIDE + k] = W2[l][k][j]
    for (int idx = tid; idx < N_LAYERS * ENT * ENT; idx += 1024) {
        const int l = idx >> 12;
        const int r = idx & 4095;
        const int k = r >> 6;
        const int j = r & 63;
        W2t[l][j * WSTRIDE + k] = W2[idx];
        Mt[l][j * WSTRIDE + k]  = Mw[idx];
    }
    for (int idx = tid; idx < N_LAYERS * ENT; idx += 1024) {
        const int l = idx >> 6, j = idx & 63;
        b1s[l][j] = b1[idx];
        b2s[l][j] = b2[idx];
        gs[l][j]  = gamma[idx];
        bs[l][j]  = beta[idx];
    }
    __syncthreads();

    const int lane = tid & 63;
    const int wv = tid >> 6;
    const int gwave = (blockIdx.x << 4) + wv;
    const int nwaves = gridDim.x << 4;

    // Bell row for lanes 0..3 (proj[j] = sum_k m[k]*bell[j][k])
    float bl0 = 0.f, bl1 = 0.f, bl2 = 0.f, bl3 = 0.f;
    if (lane < 4) {
        bl0 = bell[lane * 4 + 0];
        bl1 = bell[lane * 4 + 1];
        bl2 = bell[lane * 4 + 2];
        bl3 = bell[lane * 4 + 3];
    }

    for (int e = gwave; e < E; e += nwaves) {
        const int row = ei[e];
        const int col = ei[E + e];

        // prefetch all 6 gathers (L2/L3-resident P)
        float p1[N_LAYERS], p2[N_LAYERS];
#pragma unroll
        for (int l = 0; l < N_LAYERS; ++l) {
            p1[l] = P[row * 384 + l * 128 + lane];
            p2[l] = P[col * 384 + l * 128 + 64 + lane];
        }

        float tot = 0.f;
#pragma unroll
        for (int l = 0; l < N_LAYERS; ++l) {
            // layer input: tanh(nf[row]@W1top + nf[col]@W1bot + b1)
            const float h = tanhf(p1[l] + p2[l] + b1s[l][lane]);

            __builtin_amdgcn_wave_barrier();
            hbuf[wv][lane] = h;
            __builtin_amdgcn_wave_barrier();

            // h @ W2 + b2  (lane j: dot(hbuf[wv][:], W2t[l][j*WS:]))
            float acc = b2s[l][lane];
            const float* wrow = &W2t[l][lane * WSTRIDE];
#pragma unroll
            for (int k = 0; k < ENT; k += 4) {
                const float4 hv = *(const float4*)&hbuf[wv][k];
                const float4 w4 = *(const float4*)&wrow[k];
                acc += hv.x * w4.x + hv.y * w4.y + hv.z * w4.z + hv.w * w4.w;
            }

            // LayerNorm over 64 channels
            const float mu = wave_sum(acc) * (1.0f / 64.0f);
            const float d = acc - mu;
            const float var = wave_sum(d * d) * (1.0f / 64.0f);
            const float hn = d * (1.0f / sqrtf(var + 1e-5f)) * gs[l][lane] + bs[l][lane];

            __builtin_amdgcn_wave_barrier();
            hbuf[wv][lane] = hn;
            __builtin_amdgcn_wave_barrier();

            // m = hn @ M
            float m = 0.f;
            const float* mrow = &Mt[l][lane * WSTRIDE];
#pragma unroll
            for (int k = 0; k < ENT; k += 4) {
                const float4 hv = *(const float4*)&hbuf[wv][k];
                const float4 w4 = *(const float4*)&mrow[k];
                m += hv.x * w4.x + hv.y * w4.y + hv.z * w4.z + hv.w * w4.w;
            }

            // Bell projection on first 4 channels
            const float m0 = __shfl(m, 0, 64);
            const float m1 = __shfl(m, 1, 64);
            const float m2 = __shfl(m, 2, 64);
            const float m3 = __shfl(m, 3, 64);
            float add;
            if (lane < 4) add = bl0 * m0 + bl1 * m1 + bl2 * m2 + bl3 * m3;
            else          add = m;
            tot += add;
        }

        // L2 normalize
        const float n2 = wave_sum(tot * tot);
        const float inv = 1.0f / (sqrtf(n2) + 1e-8f);
        out[e * 64 + lane] = tot * inv;
    }
}

extern "C" void kernel_launch(void* const* d_in, const int* in_sizes, int n_in,
                              void* d_out, int out_size, void* d_ws, size_t ws_size,
                              hipStream_t stream) {
    const float* nf    = (const float*)d_in[0];
    const int*   ei    = (const int*)d_in[1];
    const float* W1    = (const float*)d_in[2];
    const float* b1    = (const float*)d_in[3];
    const float* W2    = (const float*)d_in[4];
    const float* b2    = (const float*)d_in[5];
    const float* gamma = (const float*)d_in[6];
    const float* beta  = (const float*)d_in[7];
    const float* Mw    = (const float*)d_in[8];
    const float* bell  = (const float*)d_in[9];
    float* out = (float*)d_out;
    float* P   = (float*)d_ws;   // [nNodes][384] f32 = 76.8 MB

    const int nNodes = in_sizes[0] / NODE_DIM;
    const int E = in_sizes[1] / 2;

    const int grid1 = (nNodes + 15) / 16;
    proj_kernel<<<grid1, 384, 0, stream>>>(nf, W1, P, nNodes);

    edge_kernel<<<256, 1024, 0, stream>>>(P, ei, b1, W2, b2, gamma, beta, Mw,
                                          bell, out, E);
}

// Round 2
// 715.313 us; speedup vs baseline: 2.5935x; 2.5935x over previous
//
#include <hip/hip_runtime.h>
#include <hip/hip_bf16.h>
#include <math.h>

#define N_LAYERS 3
#define ENT 64
#define NODE_DIM 128
#define PSTR 384

typedef __attribute__((ext_vector_type(8))) short bf16x8;
typedef __attribute__((ext_vector_type(4))) float f32x4;

__device__ __forceinline__ unsigned f2bf_bits(float x) {
    unsigned u = __float_as_uint(x);
    return (u + 0x7fffu + ((u >> 16) & 1u)) >> 16;   // RNE f32->bf16
}

__device__ __forceinline__ float tanh_fast(float x) {
    x = fminf(20.0f, fmaxf(-20.0f, x));
    const float e = __builtin_amdgcn_exp2f(x * 2.8853900817779268f);  // e^(2x)
    return (e - 1.0f) * __builtin_amdgcn_rcpf(e + 1.0f);
}

// ---------------- Kernel 1: per-node projection P = nf @ W1 (both halves) ----
// P[n][l*128 + s*64 + j] = sum_k nf[n][k] * W1[l][s*128+k][j]
__global__ __launch_bounds__(384) void proj_kernel(
    const float* __restrict__ nf, const float* __restrict__ W1,
    float* __restrict__ P, int nNodes)
{
    __shared__ float nfs[16 * NODE_DIM];
    const int tid = threadIdx.x;
    const int n0 = blockIdx.x * 16;

    for (int i = tid; i < 16 * NODE_DIM; i += 384) {
        int g = n0 * NODE_DIM + i;
        nfs[i] = (g < nNodes * NODE_DIM) ? nf[g] : 0.f;
    }
    __syncthreads();

    const int l = tid >> 7;
    const int rem = tid & 127;
    const int s = rem >> 6;
    const int j = rem & 63;
    const float* wp = W1 + (l * 256 + s * 128) * 64 + j;

    float acc[16];
#pragma unroll
    for (int i = 0; i < 16; ++i) acc[i] = 0.f;

    for (int k = 0; k < NODE_DIM; k += 4) {
        const float w0 = wp[(k + 0) * 64];
        const float w1 = wp[(k + 1) * 64];
        const float w2 = wp[(k + 2) * 64];
        const float w3 = wp[(k + 3) * 64];
#pragma unroll
        for (int i = 0; i < 16; ++i) {
            const float4 v = *(const float4*)&nfs[i * NODE_DIM + k];
            acc[i] += v.x * w0 + v.y * w1 + v.z * w2 + v.w * w3;
        }
    }
#pragma unroll
    for (int i = 0; i < 16; ++i) {
        int n = n0 + i;
        if (n < nNodes) P[n * PSTR + tid] = acc[i];
    }
}

// ---------------- Kernel 2: build bf16 B-fragments of W2 / M --------------
// frag id: mat = l*2 + {0:W2, 1:M}; frag = t*2 + s (t: N-tile 0..3, s: K-step 0..1)
// lane holds B[k = s*32 + (lane>>4)*8 + j][n = t*16 + (lane&15)], j=0..7
__global__ __launch_bounds__(256) void build_frags(
    const float* __restrict__ W2, const float* __restrict__ Mw,
    short* __restrict__ frags)
{
    const int id = blockIdx.x * 256 + threadIdx.x;
    if (id >= 6 * 8 * 64) return;
    const int lane = id & 63;
    const int frag = (id >> 6) & 7;
    const int mat = id >> 9;
    const int l = mat >> 1;
    const float* W = (mat & 1) ? Mw : W2;
    const int t = frag >> 1, s = frag & 1;
    const int n = t * 16 + (lane & 15);
    const int k0 = s * 32 + ((lane >> 4) * 8);
    short* dst = frags + ((mat * 8 + frag) * 64 + lane) * 8;
#pragma unroll
    for (int j = 0; j < 8; ++j)
        dst[j] = (short)f2bf_bits(W[l * 4096 + (k0 + j) * 64 + n]);
}

// ---------------- Kernel 3: fused per-edge pipeline, MFMA matvecs ----------
__global__ __launch_bounds__(256, 2) void edge_mfma(
    const float* __restrict__ P, const int* __restrict__ ei,
    const float* __restrict__ b1, const float* __restrict__ b2,
    const float* __restrict__ gamma, const float* __restrict__ beta,
    const short* __restrict__ frags, float* __restrict__ out, int E)
{
    __shared__ __align__(16) float tr[4][16 * 68];   // per-wave transpose buf, pad 68
    const int tid = threadIdx.x;
    const int lane = tid & 63;
    const int wv = tid >> 6;
    float* mytr = tr[wv];

    const int lgrp = lane >> 4;   // 0..3
    const int lmod = lane & 15;   // 0..15

    // bell bpermute lane sources (byte addresses)
    const int gbase = lane & 48;
    const int sA = (lmod < 4) ? (gbase + (lmod >> 1)) : lane;
    const int sB = (lmod < 4) ? (gbase + 3 - (lmod >> 1)) : lane;
    const int idxA = sA << 2, idxB = sB << 2;
    const float signB = (lmod & 1) ? -0.70710678118f : 0.70710678118f;

    const bf16x8* fb = (const bf16x8*)frags;

    const int nb = (E + 31) >> 5;               // batches of 32 edges
    const int gw = (blockIdx.x << 2) + wv;
    const int nw = gridDim.x << 2;

    for (int b = gw; b < nb; b += nw) {
        const int e0 = b << 5;
        int rn[2], cn[2];
#pragma unroll
        for (int mt = 0; mt < 2; ++mt) {
            int e = e0 + mt * 16 + lmod;
            int ec = (e < E) ? e : (E - 1);
            rn[mt] = ei[ec];
            cn[mt] = ei[E + ec];
        }

        f32x4 tot[2][4];
#pragma unroll
        for (int mt = 0; mt < 2; ++mt)
#pragma unroll
            for (int t = 0; t < 4; ++t) tot[mt][t] = (f32x4){0.f, 0.f, 0.f, 0.f};

#pragma unroll
        for (int l = 0; l < N_LAYERS; ++l) {
            // weight B-fragments (coalesced 16B/lane, L2-hot)
            bf16x8 w2f[4][2], mf[4][2];
#pragma unroll
            for (int t = 0; t < 4; ++t)
#pragma unroll
                for (int s = 0; s < 2; ++s) {
                    w2f[t][s] = fb[((l * 2) * 8 + t * 2 + s) * 64 + lane];
                    mf[t][s]  = fb[((l * 2 + 1) * 8 + t * 2 + s) * 64 + lane];
                }
            // b1 slice for my k-rows
            float b1v[2][8];
#pragma unroll
            for (int s = 0; s < 2; ++s) {
                const float4 t0 = *(const float4*)(b1 + l * 64 + s * 32 + lgrp * 8);
                const float4 t1 = *(const float4*)(b1 + l * 64 + s * 32 + lgrp * 8 + 4);
                b1v[s][0] = t0.x; b1v[s][1] = t0.y; b1v[s][2] = t0.z; b1v[s][3] = t0.w;
                b1v[s][4] = t1.x; b1v[s][5] = t1.y; b1v[s][6] = t1.z; b1v[s][7] = t1.w;
            }
            // per-channel params for my columns c = lmod + 16t
            float b2v[4], gv[4], bev[4];
#pragma unroll
            for (int t = 0; t < 4; ++t) {
                b2v[t] = b2[l * 64 + t * 16 + lmod];
                gv[t]  = gamma[l * 64 + t * 16 + lmod];
                bev[t] = beta[l * 64 + t * 16 + lmod];
            }

#pragma unroll
            for (int mt = 0; mt < 2; ++mt) {
                // --- build A-frag of H = tanh(p1 + p2 + b1) straight from gathers
                bf16x8 a[2];
#pragma unroll
                for (int s = 0; s < 2; ++s) {
                    const float* p1 = P + ((long)rn[mt] * PSTR + l * 128 + s * 32 + lgrp * 8);
                    const float* p2 = P + ((long)cn[mt] * PSTR + l * 128 + 64 + s * 32 + lgrp * 8);
                    const float4 a0 = *(const float4*)p1;
                    const float4 a1 = *(const float4*)(p1 + 4);
                    const float4 c0 = *(const float4*)p2;
                    const float4 c1v = *(const float4*)(p2 + 4);
                    float h[8];
                    h[0] = tanh_fast(a0.x + c0.x + b1v[s][0]);
                    h[1] = tanh_fast(a0.y + c0.y + b1v[s][1]);
                    h[2] = tanh_fast(a0.z + c0.z + b1v[s][2]);
                    h[3] = tanh_fast(a0.w + c0.w + b1v[s][3]);
                    h[4] = tanh_fast(a1.x + c1v.x + b1v[s][4]);
                    h[5] = tanh_fast(a1.y + c1v.y + b1v[s][5]);
                    h[6] = tanh_fast(a1.z + c1v.z + b1v[s][6]);
                    h[7] = tanh_fast(a1.w + c1v.w + b1v[s][7]);
                    bf16x8 av;
#pragma unroll
                    for (int j = 0; j < 8; ++j) av[j] = (short)f2bf_bits(h[j]);
                    a[s] = av;
                }

                // --- C1 = H @ W2 + b2
                f32x4 c1[4];
#pragma unroll
                for (int t = 0; t < 4; ++t)
                    c1[t] = (f32x4){b2v[t], b2v[t], b2v[t], b2v[t]};
#pragma unroll
                for (int t = 0; t < 4; ++t)
#pragma unroll
                    for (int s = 0; s < 2; ++s)
                        c1[t] = __builtin_amdgcn_mfma_f32_16x16x32_bf16(a[s], w2f[t][s], c1[t], 0, 0, 0);

                // --- LayerNorm rows + write normalized to LDS (pad-68)
#pragma unroll
                for (int r = 0; r < 4; ++r) {
                    float s1 = c1[0][r] + c1[1][r] + c1[2][r] + c1[3][r];
                    float s2 = c1[0][r] * c1[0][r] + c1[1][r] * c1[1][r]
                             + c1[2][r] * c1[2][r] + c1[3][r] * c1[3][r];
#pragma unroll
                    for (int off = 1; off < 16; off <<= 1) {
                        s1 += __shfl_xor(s1, off, 64);
                        s2 += __shfl_xor(s2, off, 64);
                    }
                    const float mu = s1 * 0.015625f;
                    const float var = s2 * 0.015625f - mu * mu;
                    const float rs = 1.0f / sqrtf(var + 1e-5f);
                    const int rowbase = (lgrp * 4 + r) * 68;
#pragma unroll
                    for (int t = 0; t < 4; ++t) {
                        const float hn = (c1[t][r] - mu) * rs * gv[t] + bev[t];
                        mytr[rowbase + lmod + 16 * t] = hn;
                    }
                }

                // --- transpose-read as A-frag (row = lmod, k = s*32 + lgrp*8 + j)
                bf16x8 a2[2];
#pragma unroll
                for (int s = 0; s < 2; ++s) {
                    const float* rp = mytr + lmod * 68 + s * 32 + lgrp * 8;
                    const float4 q0 = *(const float4*)rp;
                    const float4 q1 = *(const float4*)(rp + 4);
                    bf16x8 av;
                    av[0] = (short)f2bf_bits(q0.x); av[1] = (short)f2bf_bits(q0.y);
                    av[2] = (short)f2bf_bits(q0.z); av[3] = (short)f2bf_bits(q0.w);
                    av[4] = (short)f2bf_bits(q1.x); av[5] = (short)f2bf_bits(q1.y);
                    av[6] = (short)f2bf_bits(q1.z); av[7] = (short)f2bf_bits(q1.w);
                    a2[s] = av;
                }

                // --- C2 = Hn @ M
                f32x4 c2[4];
#pragma unroll
                for (int t = 0; t < 4; ++t) c2[t] = (f32x4){0.f, 0.f, 0.f, 0.f};
#pragma unroll
                for (int t = 0; t < 4; ++t)
#pragma unroll
                    for (int s = 0; s < 2; ++s)
                        c2[t] = __builtin_amdgcn_mfma_f32_16x16x32_bf16(a2[s], mf[t][s], c2[t], 0, 0, 0);

                // --- Bell projection on channels 0..3, accumulate into tot
#pragma unroll
                for (int r = 0; r < 4; ++r) {
                    const float m0 = c2[0][r];
                    const float vA = __int_as_float(__builtin_amdgcn_ds_bpermute(idxA, __float_as_int(m0)));
                    const float vB = __int_as_float(__builtin_amdgcn_ds_bpermute(idxB, __float_as_int(m0)));
                    const float mixed = vA * 0.70710678118f + vB * signB;
                    tot[mt][0][r] += (lmod < 4) ? mixed : m0;
                }
#pragma unroll
                for (int t = 1; t < 4; ++t) tot[mt][t] += c2[t];
            } // mt
        } // l

        // --- L2 normalize rows and store
#pragma unroll
        for (int mt = 0; mt < 2; ++mt) {
#pragma unroll
            for (int r = 0; r < 4; ++r) {
                float q = tot[mt][0][r] * tot[mt][0][r] + tot[mt][1][r] * tot[mt][1][r]
                        + tot[mt][2][r] * tot[mt][2][r] + tot[mt][3][r] * tot[mt][3][r];
#pragma unroll
                for (int off = 1; off < 16; off <<= 1) q += __shfl_xor(q, off, 64);
                const float inv = 1.0f / (sqrtf(q) + 1e-8f);
                const int e = e0 + mt * 16 + lgrp * 4 + r;
                if (e < E) {
                    float* op = out + (long)e * 64 + lmod;
#pragma unroll
                    for (int t = 0; t < 4; ++t) op[16 * t] = tot[mt][t][r] * inv;
                }
            }
        }
    }
}

extern "C" void kernel_launch(void* const* d_in, const int* in_sizes, int n_in,
                              void* d_out, int out_size, void* d_ws, size_t ws_size,
                              hipStream_t stream) {
    const float* nf    = (const float*)d_in[0];
    const int*   ei    = (const int*)d_in[1];
    const float* W1    = (const float*)d_in[2];
    const float* b1    = (const float*)d_in[3];
    const float* W2    = (const float*)d_in[4];
    const float* b2    = (const float*)d_in[5];
    const float* gamma = (const float*)d_in[6];
    const float* beta  = (const float*)d_in[7];
    const float* Mw    = (const float*)d_in[8];
    float* out = (float*)d_out;

    const int nNodes = in_sizes[0] / NODE_DIM;
    const int E = in_sizes[1] / 2;

    float* P     = (float*)d_ws;                                   // [nNodes][384] f32
    short* frags = (short*)((char*)d_ws + (size_t)nNodes * PSTR * 4); // 48 KB

    proj_kernel<<<(nNodes + 15) / 16, 384, 0, stream>>>(nf, W1, P, nNodes);
    build_frags<<<12, 256, 0, stream>>>(W2, Mw, frags);
    edge_mfma<<<1024, 256, 0, stream>>>(P, ei, b1, b2, gamma, beta, frags, out, E);
}

// Round 3
// 562.642 us; speedup vs baseline: 3.2973x; 1.2713x over previous
//
#include <hip/hip_runtime.h>
#include <hip/hip_bf16.h>
#include <math.h>

#define N_LAYERS 3
#define ENT 64
#define NODE_DIM 128
#define PROW 192   // 3 layers * 64, fp16

typedef __attribute__((ext_vector_type(8))) short bf16x8;
typedef __attribute__((ext_vector_type(8))) unsigned short u16x8;
typedef __attribute__((ext_vector_type(4))) float f32x4;

__device__ __forceinline__ unsigned f2bf_bits(float x) {
    unsigned u = __float_as_uint(x);
    return (u + 0x7fffu + ((u >> 16) & 1u)) >> 16;   // RNE f32->bf16
}

__device__ __forceinline__ float h2f(unsigned short u) {
    return (float)__builtin_bit_cast(_Float16, u);
}

__device__ __forceinline__ float tanh_fast(float x) {
    x = fminf(20.0f, fmaxf(-20.0f, x));
    const float e = __builtin_amdgcn_exp2f(x * 2.8853900817779268f);  // e^(2x)
    return (e - 1.0f) * __builtin_amdgcn_rcpf(e + 1.0f);
}

// ---------------- Kernel 1: per-node projection, fp16 split output ----------
// Prow[n][l*64+j] = sum_k nf[n][k]*W1[l][k][j] + b1[l][j]      (k = 0..127)
// Pcol[n][l*64+j] = sum_k nf[n][k]*W1[l][128+k][j]
__global__ __launch_bounds__(384) void proj_kernel(
    const float* __restrict__ nf, const float* __restrict__ W1,
    const float* __restrict__ b1,
    _Float16* __restrict__ Prow, _Float16* __restrict__ Pcol, int nNodes)
{
    __shared__ float nfs[16 * NODE_DIM];
    const int tid = threadIdx.x;
    const int n0 = blockIdx.x * 16;

    for (int i = tid; i < 16 * NODE_DIM; i += 384) {
        int g = n0 * NODE_DIM + i;
        nfs[i] = (g < nNodes * NODE_DIM) ? nf[g] : 0.f;
    }
    __syncthreads();

    const int l = tid >> 7;
    const int rem = tid & 127;
    const int s = rem >> 6;
    const int j = rem & 63;
    const float* wp = W1 + (l * 256 + s * 128) * 64 + j;
    const float badd = (s == 0) ? b1[l * 64 + j] : 0.f;

    float acc[16];
#pragma unroll
    for (int i = 0; i < 16; ++i) acc[i] = badd;

    for (int k = 0; k < NODE_DIM; k += 4) {
        const float w0 = wp[(k + 0) * 64];
        const float w1 = wp[(k + 1) * 64];
        const float w2 = wp[(k + 2) * 64];
        const float w3 = wp[(k + 3) * 64];
#pragma unroll
        for (int i = 0; i < 16; ++i) {
            const float4 v = *(const float4*)&nfs[i * NODE_DIM + k];
            acc[i] += v.x * w0 + v.y * w1 + v.z * w2 + v.w * w3;
        }
    }
    _Float16* dst = (s == 0) ? Prow : Pcol;
#pragma unroll
    for (int i = 0; i < 16; ++i) {
        int n = n0 + i;
        if (n < nNodes) dst[(long)n * PROW + l * 64 + j] = (_Float16)acc[i];
    }
}

// ---------------- Kernel 2: build bf16 B-fragments of W2 / M --------------
// frag id: mat = l*2 + {0:W2, 1:M}; frag = t*2 + s (t: N-tile 0..3, s: K-step)
// lane holds B[k = s*32 + (lane>>4)*8 + j][n = t*16 + (lane&15)], j=0..7
__global__ __launch_bounds__(256) void build_frags(
    const float* __restrict__ W2, const float* __restrict__ Mw,
    short* __restrict__ frags)
{
    const int id = blockIdx.x * 256 + threadIdx.x;
    if (id >= 6 * 8 * 64) return;
    const int lane = id & 63;
    const int frag = (id >> 6) & 7;
    const int mat = id >> 9;
    const int l = mat >> 1;
    const float* W = (mat & 1) ? Mw : W2;
    const int t = frag >> 1, s = frag & 1;
    const int n = t * 16 + (lane & 15);
    const int k0 = s * 32 + ((lane >> 4) * 8);
    short* dst = frags + ((mat * 8 + frag) * 64 + lane) * 8;
#pragma unroll
    for (int j = 0; j < 8; ++j)
        dst[j] = (short)f2bf_bits(W[l * 4096 + (k0 + j) * 64 + n]);
}

// ---------------- Kernel 3: fused per-edge pipeline, MFMA matvecs ----------
__global__ __launch_bounds__(256, 2) void edge_mfma(
    const _Float16* __restrict__ Prow, const _Float16* __restrict__ Pcol,
    const int* __restrict__ ei,
    const float* __restrict__ b2, const float* __restrict__ gamma,
    const float* __restrict__ beta, const short* __restrict__ frags,
    float* __restrict__ out, int E)
{
    __shared__ __align__(16) float tr[4][16 * 68];   // per-wave scratch
    const int tid = threadIdx.x;
    const int lane = tid & 63;
    const int wv = tid >> 6;
    float* mytr = tr[wv];

    const int lgrp = lane >> 4;   // 0..3
    const int lmod = lane & 15;   // 0..15

    // bell bpermute lane sources (byte addresses)
    const int gbase = lane & 48;
    const int sA = (lmod < 4) ? (gbase + (lmod >> 1)) : lane;
    const int sB = (lmod < 4) ? (gbase + 3 - (lmod >> 1)) : lane;
    const int idxA = sA << 2, idxB = sB << 2;
    const float signB = (lmod & 1) ? -0.70710678118f : 0.70710678118f;

    const bf16x8* fb = (const bf16x8*)frags;

    const int nb = (E + 31) >> 5;               // batches of 32 edges
    const int gw = (blockIdx.x << 2) + wv;
    const int nw = gridDim.x << 2;

    for (int b = gw; b < nb; b += nw) {
        const int e0 = b << 5;
        int rn[2], cn[2];
#pragma unroll
        for (int mt = 0; mt < 2; ++mt) {
            int e = e0 + mt * 16 + lmod;
            int ec = (e < E) ? e : (E - 1);
            rn[mt] = ei[ec];
            cn[mt] = ei[E + ec];
        }

        f32x4 tot[2][4];
#pragma unroll
        for (int mt = 0; mt < 2; ++mt)
#pragma unroll
            for (int t = 0; t < 4; ++t) tot[mt][t] = (f32x4){0.f, 0.f, 0.f, 0.f};

#pragma unroll
        for (int l = 0; l < N_LAYERS; ++l) {
            // weight B-fragments (coalesced 16B/lane, L2-hot)
            bf16x8 w2f[4][2], mf[4][2];
#pragma unroll
            for (int t = 0; t < 4; ++t)
#pragma unroll
                for (int s = 0; s < 2; ++s) {
                    w2f[t][s] = fb[((l * 2) * 8 + t * 2 + s) * 64 + lane];
                    mf[t][s]  = fb[((l * 2 + 1) * 8 + t * 2 + s) * 64 + lane];
                }
            // per-channel params for my columns c = lmod + 16t
            float b2v[4], gv[4], bev[4];
#pragma unroll
            for (int t = 0; t < 4; ++t) {
                b2v[t] = b2[l * 64 + t * 16 + lmod];
                gv[t]  = gamma[l * 64 + t * 16 + lmod];
                bev[t] = beta[l * 64 + t * 16 + lmod];
            }

            // issue ALL gathers for this layer (8 x 16B, fp16) before compute
            u16x8 g1[2][2], g2[2][2];
#pragma unroll
            for (int mt = 0; mt < 2; ++mt)
#pragma unroll
                for (int s = 0; s < 2; ++s) {
                    const _Float16* p1 = Prow + ((long)rn[mt] * PROW + l * 64 + s * 32 + lgrp * 8);
                    const _Float16* p2 = Pcol + ((long)cn[mt] * PROW + l * 64 + s * 32 + lgrp * 8);
                    g1[mt][s] = *(const u16x8*)p1;
                    g2[mt][s] = *(const u16x8*)p2;
                }

#pragma unroll
            for (int mt = 0; mt < 2; ++mt) {
                // --- A-frag of H = tanh(prow + pcol) (b1 pre-folded)
                bf16x8 a[2];
#pragma unroll
                for (int s = 0; s < 2; ++s) {
                    bf16x8 av;
#pragma unroll
                    for (int j = 0; j < 8; ++j) {
                        const float h = tanh_fast(h2f(g1[mt][s][j]) + h2f(g2[mt][s][j]));
                        av[j] = (short)f2bf_bits(h);
                    }
                    a[s] = av;
                }

                // --- C1 = H @ W2 + b2
                f32x4 c1[4];
#pragma unroll
                for (int t = 0; t < 4; ++t)
                    c1[t] = (f32x4){b2v[t], b2v[t], b2v[t], b2v[t]};
#pragma unroll
                for (int t = 0; t < 4; ++t)
#pragma unroll
                    for (int s = 0; s < 2; ++s)
                        c1[t] = __builtin_amdgcn_mfma_f32_16x16x32_bf16(a[s], w2f[t][s], c1[t], 0, 0, 0);

                // --- LayerNorm rows + write normalized to LDS (pad-68)
#pragma unroll
                for (int r = 0; r < 4; ++r) {
                    float s1 = c1[0][r] + c1[1][r] + c1[2][r] + c1[3][r];
                    float s2 = c1[0][r] * c1[0][r] + c1[1][r] * c1[1][r]
                             + c1[2][r] * c1[2][r] + c1[3][r] * c1[3][r];
#pragma unroll
                    for (int off = 1; off < 16; off <<= 1) {
                        s1 += __shfl_xor(s1, off, 64);
                        s2 += __shfl_xor(s2, off, 64);
                    }
                    const float mu = s1 * 0.015625f;
                    const float var = s2 * 0.015625f - mu * mu;
                    const float rs = 1.0f / sqrtf(var + 1e-5f);
                    const int rowbase = (lgrp * 4 + r) * 68;
#pragma unroll
                    for (int t = 0; t < 4; ++t) {
                        const float hn = (c1[t][r] - mu) * rs * gv[t] + bev[t];
                        mytr[rowbase + lmod + 16 * t] = hn;
                    }
                }
                __builtin_amdgcn_wave_barrier();

                // --- transpose-read as A-frag (row = lmod, k = s*32 + lgrp*8 + j)
                bf16x8 a2[2];
#pragma unroll
                for (int s = 0; s < 2; ++s) {
                    const float* rp = mytr + lmod * 68 + s * 32 + lgrp * 8;
                    const float4 q0 = *(const float4*)rp;
                    const float4 q1 = *(const float4*)(rp + 4);
                    bf16x8 av;
                    av[0] = (short)f2bf_bits(q0.x); av[1] = (short)f2bf_bits(q0.y);
                    av[2] = (short)f2bf_bits(q0.z); av[3] = (short)f2bf_bits(q0.w);
                    av[4] = (short)f2bf_bits(q1.x); av[5] = (short)f2bf_bits(q1.y);
                    av[6] = (short)f2bf_bits(q1.z); av[7] = (short)f2bf_bits(q1.w);
                    a2[s] = av;
                }
                __builtin_amdgcn_wave_barrier();

                // --- C2 = Hn @ M
                f32x4 c2[4];
#pragma unroll
                for (int t = 0; t < 4; ++t) c2[t] = (f32x4){0.f, 0.f, 0.f, 0.f};
#pragma unroll
                for (int t = 0; t < 4; ++t)
#pragma unroll
                    for (int s = 0; s < 2; ++s)
                        c2[t] = __builtin_amdgcn_mfma_f32_16x16x32_bf16(a2[s], mf[t][s], c2[t], 0, 0, 0);

                // --- Bell projection on channels 0..3, accumulate into tot
#pragma unroll
                for (int r = 0; r < 4; ++r) {
                    const float m0 = c2[0][r];
                    const float vA = __int_as_float(__builtin_amdgcn_ds_bpermute(idxA, __float_as_int(m0)));
                    const float vB = __int_as_float(__builtin_amdgcn_ds_bpermute(idxB, __float_as_int(m0)));
                    const float mixed = vA * 0.70710678118f + vB * signB;
                    tot[mt][0][r] += (lmod < 4) ? mixed : m0;
                }
#pragma unroll
                for (int t = 1; t < 4; ++t) tot[mt][t] += c2[t];
            } // mt
        } // l

        // --- L2 normalize rows, stage in LDS, coalesced float4 store
#pragma unroll
        for (int mt = 0; mt < 2; ++mt) {
#pragma unroll
            for (int r = 0; r < 4; ++r) {
                float q = tot[mt][0][r] * tot[mt][0][r] + tot[mt][1][r] * tot[mt][1][r]
                        + tot[mt][2][r] * tot[mt][2][r] + tot[mt][3][r] * tot[mt][3][r];
#pragma unroll
                for (int off = 1; off < 16; off <<= 1) q += __shfl_xor(q, off, 64);
                const float inv = 1.0f / (sqrtf(q) + 1e-8f);
                const int rowloc = lgrp * 4 + r;
#pragma unroll
                for (int t = 0; t < 4; ++t)
                    mytr[rowloc * 64 + lmod + 16 * t] = tot[mt][t][r] * inv;
            }
            __builtin_amdgcn_wave_barrier();
#pragma unroll
            for (int i = 0; i < 4; ++i) {
                const int row = i * 4 + (lane >> 4);
                const int c4 = (lane & 15) * 4;
                const int e = e0 + mt * 16 + row;
                if (e < E) {
                    const float4 v = *(const float4*)&mytr[row * 64 + c4];
                    *(float4*)(out + (long)e * 64 + c4) = v;
                }
            }
            __builtin_amdgcn_wave_barrier();
        }
    }
}

extern "C" void kernel_launch(void* const* d_in, const int* in_sizes, int n_in,
                              void* d_out, int out_size, void* d_ws, size_t ws_size,
                              hipStream_t stream) {
    const float* nf    = (const float*)d_in[0];
    const int*   ei    = (const int*)d_in[1];
    const float* W1    = (const float*)d_in[2];
    const float* b1    = (const float*)d_in[3];
    const float* W2    = (const float*)d_in[4];
    const float* b2    = (const float*)d_in[5];
    const float* gamma = (const float*)d_in[6];
    const float* beta  = (const float*)d_in[7];
    const float* Mw    = (const float*)d_in[8];
    float* out = (float*)d_out;

    const int nNodes = in_sizes[0] / NODE_DIM;
    const int E = in_sizes[1] / 2;

    _Float16* Prow = (_Float16*)d_ws;
    _Float16* Pcol = Prow + (size_t)nNodes * PROW;
    short* frags   = (short*)(Pcol + (size_t)nNodes * PROW);

    proj_kernel<<<(nNodes + 15) / 16, 384, 0, stream>>>(nf, W1, b1, Prow, Pcol, nNodes);
    build_frags<<<12, 256, 0, stream>>>(W2, Mw, frags);
    edge_mfma<<<2048, 256, 0, stream>>>(Prow, Pcol, ei, b2, gamma, beta, frags, out, E);
}